// Round 6
// baseline (744.001 us; speedup 1.0000x reference)
//
#include <hip/hip_runtime.h>
#include <math.h>

#define BB   8
#define NN   1024
#define SS   128
#define KK   32
#define EMB  384

// padded K strides (elements) for transposed split weights
#define KP1  136   // W1bt [256][136]
#define KP2  264   // W2at [512][264]
#define KP3  520   // W2bt [384][520]

typedef __attribute__((ext_vector_type(4))) float f32x4;
typedef __attribute__((ext_vector_type(8))) short s16x8;

__device__ __forceinline__ unsigned short f2bf(float x) {
    unsigned u = __float_as_uint(x);
    unsigned r = (u + 0x7FFFu + ((u >> 16) & 1u)) >> 16;   // RN-even
    return (unsigned short)r;
}
__device__ __forceinline__ float bf2f(unsigned short h) {
    return __uint_as_float(((unsigned)h) << 16);
}
__device__ __forceinline__ f32x4 mfma16(s16x8 a, s16x8 b, f32x4 c) {
    return __builtin_amdgcn_mfma_f32_16x16x32_bf16(a, b, c, 0, 0, 0);
}

// ---------------------------------------------------------------------------
// pre_kernel: blocks 0..7 = FPS (one wave per cloud, LDS-atomic argmax:
// key = (d_bits<<10)|(1023-idx); u64 max == max-d, ties -> lowest idx. EXACT,
// same total order as the verified butterfly; d >= 0 finite so IEEE bits are
// monotonic). blocks 8..359 = tiled transpose + bf16 hi/lo weight split.
// ---------------------------------------------------------------------------
__global__ __launch_bounds__(256) void pre_kernel(
    const float* __restrict__ pos, float* __restrict__ seed_pos,
    const float* __restrict__ W1b, const float* __restrict__ W2a,
    const float* __restrict__ W2b,
    unsigned short* __restrict__ W1bt_h, unsigned short* __restrict__ W1bt_l,
    unsigned short* __restrict__ W2at_h, unsigned short* __restrict__ W2at_l,
    unsigned short* __restrict__ W2bt_h, unsigned short* __restrict__ W2bt_l)
{
    __shared__ float s_cloud[3][NN];          // FPS path (12 KB)
    __shared__ unsigned long long s_key;      // FPS argmax slot
    __shared__ float tile[32][33];            // prep path
    const int bid = blockIdx.x;
    if (bid < BB) {
        // ---------------- FPS ----------------
        const int b = bid;
        const float* p = pos + (size_t)b * NN * 3;
        for (int k = 0; k < 4; ++k) {
            const int i = threadIdx.x + k * 256;
            s_cloud[0][i] = p[i * 3 + 0];
            s_cloud[1][i] = p[i * 3 + 1];
            s_cloud[2][i] = p[i * 3 + 2];
        }
        __syncthreads();
        if (threadIdx.x >= 64) return;        // single wave from here on
        const int l = threadIdx.x;
        if (l == 0) s_key = 0ull;

        float px[16], py[16], pz[16], mind[16];
#pragma unroll
        for (int r = 0; r < 16; ++r) {
            const int i = r * 64 + l;
            px[r] = s_cloud[0][i];
            py[r] = s_cloud[1][i];
            pz[r] = s_cloud[2][i];
            mind[r] = INFINITY;
        }

        int gi = 0;                           // current seed index (uniform)
        for (int s = 0; s < SS; ++s) {
            const float sxv = s_cloud[0][gi];
            const float syv = s_cloud[1][gi];
            const float szv = s_cloud[2][gi];
            if (l == 0) {
                seed_pos[((size_t)b * SS + s) * 3 + 0] = sxv;
                seed_pos[((size_t)b * SS + s) * 3 + 1] = syv;
                seed_pos[((size_t)b * SS + s) * 3 + 2] = szv;
            }
            if (s == SS - 1) break;
            // exact np-order distance: ((dx*dx + dy*dy) + dz*dz), no FMA
#pragma unroll
            for (int r = 0; r < 16; ++r) {
                const float dx = __fsub_rn(px[r], sxv);
                const float dy = __fsub_rn(py[r], syv);
                const float dz = __fsub_rn(pz[r], szv);
                const float d = __fadd_rn(__fadd_rn(__fmul_rn(dx, dx), __fmul_rn(dy, dy)),
                                          __fmul_rn(dz, dz));
                mind[r] = fminf(mind[r], d);
            }
            // local 4-level argmax tree over 16 regs (ties -> lowest idx)
            float td[16]; int ti[16];
#pragma unroll
            for (int r = 0; r < 16; ++r) { td[r] = mind[r]; ti[r] = r * 64 + l; }
#pragma unroll
            for (int off = 8; off >= 1; off >>= 1) {
#pragma unroll
                for (int r = 0; r < 8; ++r) {
                    if (r < off) {
                        const bool take = (td[r + off] > td[r]) ||
                                          (td[r + off] == td[r] && ti[r + off] < ti[r]);
                        td[r] = take ? td[r + off] : td[r];
                        ti[r] = take ? ti[r + off] : ti[r];
                    }
                }
            }
            // cross-lane argmax: one packed u64 LDS atomic per lane.
            // Per-wave DS ordering: all 64 ds_max precede the wave's read;
            // the lane-0 reset write follows the read; next iter's ds_max
            // follows the reset. No barrier needed (single wave).
            const unsigned long long key =
                ((unsigned long long)__float_as_uint(td[0]) << 10) |
                (unsigned long long)(1023 - ti[0]);
            atomicMax(&s_key, key);
            __threadfence_block();
            const unsigned long long win = *(volatile unsigned long long*)&s_key;
            gi = 1023 - (int)(win & 1023ull);
            if (l == 0) *(volatile unsigned long long*)&s_key = 0ull;
        }
        return;
    }

    // ---------------- weight prep: 32x32 tile transpose + split ----------------
    int tid = bid - BB;
    const float* src;
    unsigned short *dh, *dl;
    int N, Kp, koff, kt, nt;
    if (tid < 32) {
        src = W1b; dh = W1bt_h; dl = W1bt_l; N = 256; Kp = KP1; koff = 0;
        kt = tid >> 3; nt = tid & 7;
    } else if (tid < 160) {
        tid -= 32;
        src = W2a; dh = W2at_h; dl = W2at_l; N = 512; Kp = KP2; koff = 256;
        kt = tid >> 4; nt = tid & 15;
    } else {
        tid -= 160;
        src = W2b; dh = W2bt_h; dl = W2bt_l; N = 384; Kp = KP3; koff = 0;
        kt = tid / 12; nt = tid % 12;
    }
    const int k0 = kt * 32, n0 = nt * 32;
    const int tx = threadIdx.x & 31, ty = threadIdx.x >> 5;
#pragma unroll
    for (int i = 0; i < 4; ++i) {
        const int kl = ty + i * 8;
        tile[kl][tx] = src[(size_t)(k0 + kl + koff) * N + n0 + tx];
    }
    __syncthreads();
#pragma unroll
    for (int i = 0; i < 4; ++i) {
        const int nl = ty + i * 8;
        const float x = tile[tx][nl];
        const unsigned short hi = f2bf(x);
        const unsigned short lo = f2bf(x - bf2f(hi));
        const size_t o = (size_t)(n0 + nl) * Kp + k0 + tx;
        dh[o] = hi;
        dl[o] = lo;
    }
}

// ---------------------------------------------------------------------------
// kNN: wave-per-seed, shfl butterfly argmin (verified rounds 3-4).
// ---------------------------------------------------------------------------
__global__ __launch_bounds__(512) void knn_kernel(
    const float* __restrict__ pos,
    const float* __restrict__ seed_pos,
    int* __restrict__ nbr)
{
    __shared__ float sx_[NN], sy_[NN], sz_[NN];
    const int blk = blockIdx.x;            // 0..127
    const int b   = blk >> 4;
    const int t   = threadIdx.x;
    const int w   = t >> 6;
    const int l   = t & 63;
    const float* p = pos + (size_t)b * NN * 3;

    for (int i = t; i < NN; i += 512) {
        sx_[i] = p[i * 3 + 0];
        sy_[i] = p[i * 3 + 1];
        sz_[i] = p[i * 3 + 2];
    }
    __syncthreads();

    const int gsid = b * SS + (blk & 15) * 8 + w;
    const float cx = seed_pos[gsid * 3 + 0];
    const float cy = seed_pos[gsid * 3 + 1];
    const float cz = seed_pos[gsid * 3 + 2];

    float d[16];
#pragma unroll
    for (int r = 0; r < 16; ++r) {
        const int i = r * 64 + l;
        const float dx = __fsub_rn(sx_[i], cx);
        const float dy = __fsub_rn(sy_[i], cy);
        const float dz = __fsub_rn(sz_[i], cz);
        d[r] = __fadd_rn(__fadd_rn(__fmul_rn(dx, dx), __fmul_rn(dy, dy)),
                         __fmul_rn(dz, dz));
    }

    for (int it = 0; it < KK; ++it) {
        float best = INFINITY;
        int bi = NN;
#pragma unroll
        for (int r = 0; r < 16; ++r) {
            if (d[r] < best) { best = d[r]; bi = r * 64 + l; }
        }
#pragma unroll
        for (int off = 1; off < 64; off <<= 1) {
            const float ov = __shfl_xor(best, off);
            const int   oi = __shfl_xor(bi, off);
            if (ov < best || (ov == best && oi < bi)) { best = ov; bi = oi; }
        }
        const int wr = bi >> 6, wl = bi & 63;
#pragma unroll
        for (int r = 0; r < 16; ++r) {
            if (r == wr && l == wl) d[r] = INFINITY;
        }
        if (l == 0) nbr[(size_t)gsid * KK + it] = bi;
    }
}

// ---------------------------------------------------------------------------
// PointConv, M=64 (2 seeds per block), 8 waves (512 threads) — verified R4.
// ---------------------------------------------------------------------------
__global__ __launch_bounds__(512, 2) void conv_kernel(
    const float* __restrict__ pos,
    const float* __restrict__ seed_pos,
    const int* __restrict__ nbr,
    const float* __restrict__ W1a, const float* __restrict__ b1a,
    const float* __restrict__ b1b,
    const float* __restrict__ W2a, const float* __restrict__ b2a,
    const float* __restrict__ b2b,
    const unsigned short* __restrict__ W1bt_h, const unsigned short* __restrict__ W1bt_l,
    const unsigned short* __restrict__ W2at_h, const unsigned short* __restrict__ W2at_l,
    const unsigned short* __restrict__ W2bt_h, const unsigned short* __restrict__ W2bt_l,
    float* __restrict__ out)
{
    __shared__ __align__(16) unsigned char smem[105216];
    unsigned char* sH1h = smem;
    unsigned char* sH1l = smem + 16384;
    unsigned char* sA2h = smem + 32768;
    unsigned char* sA2l = smem + 65536;
    unsigned char* sA3h = smem;
    unsigned char* sA3l = smem + 32768;
    float* s_g    = (float*)(smem + 98304);    // [2][256]
    float* s_base = (float*)(smem + 100352);   // [2][512]
    float* s_rel  = (float*)(smem + 104448);   // [64][3]

    const int blk = blockIdx.x;                // seeds blk*2, blk*2+1
    const int t   = threadIdx.x;
    const int w   = t >> 6;
    const int l   = t & 63;
    const int lg  = l >> 4;
    const int l15 = l & 15;

    // ---- stage 0: gather rel for 64 rows (2 seeds x 32 neighbors) ----
    if (t < 64) {
        const int sl   = t >> 5;
        const int gsid = blk * 2 + sl;
        const int b    = gsid >> 7;
        const int pi   = nbr[(size_t)gsid * KK + (t & 31)];
        const float* pp = pos + ((size_t)b * NN + pi) * 3;
        s_rel[t * 3 + 0] = pp[0] - seed_pos[gsid * 3 + 0];
        s_rel[t * 3 + 1] = pp[1] - seed_pos[gsid * 3 + 1];
        s_rel[t * 3 + 2] = pp[2] - seed_pos[gsid * 3 + 2];
    }
    __syncthreads();

    // ---- stage 1: h1[64][128] = relu(rel@W1a + b1a) -> H1 hi/lo swizzled ----
    {
        const int j  = t & 127;
        const int rg = t >> 7;
        const float w0 = W1a[j], w1 = W1a[128 + j], w2 = W1a[256 + j], bb = b1a[j];
#pragma unroll
        for (int rr = 0; rr < 16; ++rr) {
            const int row = rg * 16 + rr;
            float v = fmaf(s_rel[row * 3 + 2], w2,
                      fmaf(s_rel[row * 3 + 1], w1,
                      fmaf(s_rel[row * 3 + 0], w0, bb)));
            v = fmaxf(v, 0.0f);
            const unsigned short hi = f2bf(v);
            const unsigned short lo = f2bf(v - bf2f(hi));
            const int byte = (j * 2) ^ ((row & 7) << 4);
            *(unsigned short*)(sH1h + row * 256 + byte) = hi;
            *(unsigned short*)(sH1l + row * 256 + byte) = lo;
        }
    }
    __syncthreads();

    // ---- GEMM1: f = h1 @ W1b (M=64,N=256,K=128) ----
    {
        f32x4 C1[4][2];
#pragma unroll
        for (int m = 0; m < 4; ++m)
#pragma unroll
            for (int i = 0; i < 2; ++i) C1[m][i] = (f32x4){0.f, 0.f, 0.f, 0.f};
#pragma unroll
        for (int ks = 0; ks < 4; ++ks) {
            s16x8 ah[4], al[4], bh[2], bl[2];
#pragma unroll
            for (int m = 0; m < 4; ++m) {
                const int row = m * 16 + l15;
                const int byte = (lg * 16 + ks * 64) ^ ((row & 7) << 4);
                ah[m] = *(const s16x8*)(sH1h + row * 256 + byte);
                al[m] = *(const s16x8*)(sH1l + row * 256 + byte);
            }
#pragma unroll
            for (int i = 0; i < 2; ++i) {
                const int ncol = w * 32 + i * 16 + l15;
                const size_t off = (size_t)ncol * KP1 + lg * 8 + ks * 32;
                bh[i] = *(const s16x8*)(W1bt_h + off);
                bl[i] = *(const s16x8*)(W1bt_l + off);
            }
#pragma unroll
            for (int i = 0; i < 2; ++i)
#pragma unroll
                for (int m = 0; m < 4; ++m) C1[m][i] = mfma16(ah[m], bh[i], C1[m][i]);
#pragma unroll
            for (int i = 0; i < 2; ++i)
#pragma unroll
                for (int m = 0; m < 4; ++m) C1[m][i] = mfma16(ah[m], bl[i], C1[m][i]);
#pragma unroll
            for (int i = 0; i < 2; ++i)
#pragma unroll
                for (int m = 0; m < 4; ++m) C1[m][i] = mfma16(al[m], bh[i], C1[m][i]);
        }
#pragma unroll
        for (int i = 0; i < 2; ++i) {
            const int col = w * 32 + i * 16 + l15;
            const float bias = b1b[col];
            float pm0 = -INFINITY, pm1 = -INFINITY;
#pragma unroll
            for (int m = 0; m < 4; ++m)
#pragma unroll
                for (int r = 0; r < 4; ++r) {
                    const float v = C1[m][i][r] + bias;
                    if (m < 2) pm0 = fmaxf(pm0, v); else pm1 = fmaxf(pm1, v);
                    const int row = m * 16 + lg * 4 + r;
                    const unsigned short hi = f2bf(v);
                    const unsigned short lo = f2bf(v - bf2f(hi));
                    const int byte = (col * 2) ^ ((row & 7) << 4);
                    *(unsigned short*)(sA2h + row * 512 + byte) = hi;
                    *(unsigned short*)(sA2l + row * 512 + byte) = lo;
                }
            pm0 = fmaxf(pm0, __shfl_xor(pm0, 16));
            pm0 = fmaxf(pm0, __shfl_xor(pm0, 32));
            pm1 = fmaxf(pm1, __shfl_xor(pm1, 16));
            pm1 = fmaxf(pm1, __shfl_xor(pm1, 32));
            if (lg == 0) { s_g[col] = pm0; s_g[256 + col] = pm1; }
        }
    }
    __syncthreads();

    // ---- base[seed][c] = b2a[c] + g_seed @ W2a[0:256] ----
    {
        const int c = t;
        float a0 = b2a[c], a1 = b2a[c];
#pragma unroll 4
        for (int jj = 0; jj < 256; ++jj) {
            const float w_ = W2a[(size_t)jj * 512 + c];
            a0 = fmaf(s_g[jj],       w_, a0);
            a1 = fmaf(s_g[256 + jj], w_, a1);
        }
        s_base[c] = a0;
        s_base[512 + c] = a1;
    }
    __syncthreads();

    // ---- GEMM2: C2 = f @ W2a[256:] (M=64,N=512,K=256) ----
    f32x4 C2[4][4];
#pragma unroll
    for (int m = 0; m < 4; ++m)
#pragma unroll
        for (int n = 0; n < 4; ++n) C2[m][n] = (f32x4){0.f, 0.f, 0.f, 0.f};
#pragma unroll 2
    for (int ks = 0; ks < 8; ++ks) {
        s16x8 ah[4], al[4];
#pragma unroll
        for (int m = 0; m < 4; ++m) {
            const int row = m * 16 + l15;
            const int byte = (lg * 16 + ks * 64) ^ ((row & 7) << 4);
            ah[m] = *(const s16x8*)(sA2h + row * 512 + byte);
            al[m] = *(const s16x8*)(sA2l + row * 512 + byte);
        }
#pragma unroll
        for (int n = 0; n < 4; ++n) {
            const int ncol = n * 128 + w * 16 + l15;
            const size_t off = (size_t)ncol * KP2 + lg * 8 + ks * 32;
            const s16x8 bh = *(const s16x8*)(W2at_h + off);
            const s16x8 bl = *(const s16x8*)(W2at_l + off);
#pragma unroll
            for (int m = 0; m < 4; ++m) C2[m][n] = mfma16(ah[m], bh, C2[m][n]);
#pragma unroll
            for (int m = 0; m < 4; ++m) C2[m][n] = mfma16(ah[m], bl, C2[m][n]);
#pragma unroll
            for (int m = 0; m < 4; ++m) C2[m][n] = mfma16(al[m], bh, C2[m][n]);
        }
    }
    __syncthreads();

    // ---- GEMM3: e = h2 @ W2b, K-split through one 64KB staging buffer ----
    f32x4 C3[4][3];
#pragma unroll
    for (int m = 0; m < 4; ++m)
#pragma unroll
        for (int n = 0; n < 3; ++n) C3[m][n] = (f32x4){0.f, 0.f, 0.f, 0.f};

#pragma unroll
    for (int h = 0; h < 2; ++h) {
#pragma unroll
        for (int q = 0; q < 2; ++q) {
            const int n = 2 * h + q;
            const int col  = n * 128 + w * 16 + l15;
            const int colL = q * 128 + w * 16 + l15;
            const float bs0 = s_base[col];
            const float bs1 = s_base[512 + col];
#pragma unroll
            for (int m = 0; m < 4; ++m)
#pragma unroll
                for (int r = 0; r < 4; ++r) {
                    const float v = fmaxf(C2[m][n][r] + (m < 2 ? bs0 : bs1), 0.0f);
                    const int row = m * 16 + lg * 4 + r;
                    const unsigned short hi = f2bf(v);
                    const unsigned short lo = f2bf(v - bf2f(hi));
                    const int byte = (colL * 2) ^ ((row & 7) << 4);
                    *(unsigned short*)(sA3h + row * 512 + byte) = hi;
                    *(unsigned short*)(sA3l + row * 512 + byte) = lo;
                }
        }
        __syncthreads();

        const int koff = h * 256;
#pragma unroll 2
        for (int ks = 0; ks < 8; ++ks) {
            s16x8 ah[4], al[4];
#pragma unroll
            for (int m = 0; m < 4; ++m) {
                const int row = m * 16 + l15;
                const int byte = (lg * 16 + ks * 64) ^ ((row & 7) << 4);
                ah[m] = *(const s16x8*)(sA3h + row * 512 + byte);
                al[m] = *(const s16x8*)(sA3l + row * 512 + byte);
            }
#pragma unroll
            for (int n = 0; n < 3; ++n) {
                const int ncol = w * 48 + n * 16 + l15;
                const size_t off = (size_t)ncol * KP3 + koff + lg * 8 + ks * 32;
                const s16x8 bh = *(const s16x8*)(W2bt_h + off);
                const s16x8 bl = *(const s16x8*)(W2bt_l + off);
#pragma unroll
                for (int m = 0; m < 4; ++m) C3[m][n] = mfma16(ah[m], bh, C3[m][n]);
#pragma unroll
                for (int m = 0; m < 4; ++m) C3[m][n] = mfma16(ah[m], bl, C3[m][n]);
#pragma unroll
                for (int m = 0; m < 4; ++m) C3[m][n] = mfma16(al[m], bh, C3[m][n]);
            }
        }
        if (h == 0) __syncthreads();
    }

    // ---- epilogue: out[seed] = colmax(e_seed) + b2b ----
#pragma unroll
    for (int n = 0; n < 3; ++n) {
        const int col = w * 48 + n * 16 + l15;
        float pm0 = -INFINITY, pm1 = -INFINITY;
#pragma unroll
        for (int m = 0; m < 4; ++m)
#pragma unroll
            for (int r = 0; r < 4; ++r) {
                if (m < 2) pm0 = fmaxf(pm0, C3[m][n][r]);
                else       pm1 = fmaxf(pm1, C3[m][n][r]);
            }
        pm0 = fmaxf(pm0, __shfl_xor(pm0, 16));
        pm0 = fmaxf(pm0, __shfl_xor(pm0, 32));
        pm1 = fmaxf(pm1, __shfl_xor(pm1, 16));
        pm1 = fmaxf(pm1, __shfl_xor(pm1, 32));
        if (lg == 0) {
            out[(size_t)(blk * 2 + 0) * EMB + col] = pm0 + b2b[col];
            out[(size_t)(blk * 2 + 1) * EMB + col] = pm1 + b2b[col];
        }
    }
}

// ---------------------------------------------------------------------------
extern "C" void kernel_launch(void* const* d_in, const int* in_sizes, int n_in,
                              void* d_out, int out_size, void* d_ws, size_t ws_size,
                              hipStream_t stream)
{
    const float* pos = (const float*)d_in[0];
    const float* W1a = (const float*)d_in[2];
    const float* b1a = (const float*)d_in[3];
    const float* W1b = (const float*)d_in[4];
    const float* b1b = (const float*)d_in[5];
    const float* W2a = (const float*)d_in[6];
    const float* b2a = (const float*)d_in[7];
    const float* W2b = (const float*)d_in[8];
    const float* b2b = (const float*)d_in[9];
    float* out = (float*)d_out;

    unsigned char* ws = (unsigned char*)d_ws;
    float* seed_pos = (float*)(ws + 0);                         // 12 KB
    int*   nbr      = (int*)(ws + 16384);                       // 128 KB
    unsigned short* W1bt_h = (unsigned short*)(ws + 147456);    // [256][136]
    unsigned short* W1bt_l = (unsigned short*)(ws + 217088);
    unsigned short* W2at_h = (unsigned short*)(ws + 286720);    // [512][264]
    unsigned short* W2at_l = (unsigned short*)(ws + 557056);
    unsigned short* W2bt_h = (unsigned short*)(ws + 827392);    // [384][520]
    unsigned short* W2bt_l = (unsigned short*)(ws + 1226752);

    pre_kernel<<<BB + 352, 256, 0, stream>>>(pos, seed_pos, W1b, W2a, W2b,
                                             W1bt_h, W1bt_l, W2at_h, W2at_l,
                                             W2bt_h, W2bt_l);
    knn_kernel<<<BB * SS / 8, 512, 0, stream>>>(pos, seed_pos, nbr);
    conv_kernel<<<BB * SS / 2, 512, 0, stream>>>(pos, seed_pos, nbr,
                                                 W1a, b1a, b1b, W2a, b2a, b2b,
                                                 W1bt_h, W1bt_l, W2at_h, W2at_l,
                                                 W2bt_h, W2bt_l, out);
}

// Round 7
// 221.119 us; speedup vs baseline: 3.3647x; 3.3647x over previous
//
#include <hip/hip_runtime.h>
#include <math.h>

#define BB   8
#define NN   1024
#define SS   128
#define KK   32
#define EMB  384

// padded K strides (elements) for transposed split weights
#define KP1  136   // W1bt [256][136]
#define KP2  264   // W2at [512][264]
#define KP3  520   // W2bt [384][520]

typedef __attribute__((ext_vector_type(4))) float f32x4;
typedef __attribute__((ext_vector_type(8))) short s16x8;

__device__ __forceinline__ unsigned short f2bf(float x) {
    unsigned u = __float_as_uint(x);
    unsigned r = (u + 0x7FFFu + ((u >> 16) & 1u)) >> 16;   // RN-even
    return (unsigned short)r;
}
__device__ __forceinline__ float bf2f(unsigned short h) {
    return __uint_as_float(((unsigned)h) << 16);
}
__device__ __forceinline__ f32x4 mfma16(s16x8 a, s16x8 b, f32x4 c) {
    return __builtin_amdgcn_mfma_f32_16x16x32_bf16(a, b, c, 0, 0, 0);
}

// ---------------------------------------------------------------------------
// pre_kernel: blocks 0..7 = FPS; blocks 8..359 = weight transpose/split.
// FPS cross-lane argmax per iteration: local VALU max tree -> one ds_write
// per lane -> 16 broadcast ds_read_b128 (all lanes same addr, conflict-free,
// independent issues) -> VALU tree over 64 values -> index via local rescan +
// __ballot + readlane (no shuffle chains, no atomics, no barriers).
// Exact tie semantics: global argmax with lowest index (min over lanes of
// per-lane min matching idx == global min matching idx).
// ---------------------------------------------------------------------------
__global__ __launch_bounds__(256) void pre_kernel(
    const float* __restrict__ pos, float* __restrict__ seed_pos,
    const float* __restrict__ W1b, const float* __restrict__ W2a,
    const float* __restrict__ W2b,
    unsigned short* __restrict__ W1bt_h, unsigned short* __restrict__ W1bt_l,
    unsigned short* __restrict__ W2at_h, unsigned short* __restrict__ W2at_l,
    unsigned short* __restrict__ W2bt_h, unsigned short* __restrict__ W2bt_l)
{
    __shared__ float s_cloud[3][NN];             // FPS path (12 KB)
    __shared__ __align__(16) float s_red[64];    // FPS reduce slots
    __shared__ float tile[32][33];               // prep path
    const int bid = blockIdx.x;
    if (bid < BB) {
        // ---------------- FPS ----------------
        const int b = bid;
        const float* p = pos + (size_t)b * NN * 3;
        for (int k = 0; k < 4; ++k) {
            const int i = threadIdx.x + k * 256;
            s_cloud[0][i] = p[i * 3 + 0];
            s_cloud[1][i] = p[i * 3 + 1];
            s_cloud[2][i] = p[i * 3 + 2];
        }
        __syncthreads();
        if (threadIdx.x >= 64) return;           // single wave from here on
        const int l = threadIdx.x;

        float px[16], py[16], pz[16], mind[16];
#pragma unroll
        for (int r = 0; r < 16; ++r) {
            const int i = r * 64 + l;
            px[r] = s_cloud[0][i];
            py[r] = s_cloud[1][i];
            pz[r] = s_cloud[2][i];
            mind[r] = INFINITY;
        }

        int gi = 0;                              // current seed idx (uniform)
        for (int s = 0; s < SS; ++s) {
            const float sxv = s_cloud[0][gi];
            const float syv = s_cloud[1][gi];
            const float szv = s_cloud[2][gi];
            if (l == 0) {
                seed_pos[((size_t)b * SS + s) * 3 + 0] = sxv;
                seed_pos[((size_t)b * SS + s) * 3 + 1] = syv;
                seed_pos[((size_t)b * SS + s) * 3 + 2] = szv;
            }
            if (s == SS - 1) break;
            // exact np-order distance: ((dx*dx + dy*dy) + dz*dz), no FMA
#pragma unroll
            for (int r = 0; r < 16; ++r) {
                const float dx = __fsub_rn(px[r], sxv);
                const float dy = __fsub_rn(py[r], syv);
                const float dz = __fsub_rn(pz[r], szv);
                const float d = __fadd_rn(__fadd_rn(__fmul_rn(dx, dx), __fmul_rn(dy, dy)),
                                          __fmul_rn(dz, dz));
                mind[r] = fminf(mind[r], d);
            }
            // local max over 16 regs: pairwise VALU tree (value only)
            float t8[8];
#pragma unroll
            for (int r = 0; r < 8; ++r) t8[r] = fmaxf(mind[r], mind[r + 8]);
            float t4a = fmaxf(t8[0], t8[4]), t4b = fmaxf(t8[1], t8[5]);
            float t4c = fmaxf(t8[2], t8[6]), t4d = fmaxf(t8[3], t8[7]);
            const float lm = fmaxf(fmaxf(t4a, t4b), fmaxf(t4c, t4d));

            s_red[l] = lm;                       // one ds_write_b32 per lane
            // broadcast reads: 16 x ds_read_b128, identical addr across lanes
            const f32x4* rp = (const f32x4*)s_red;
            f32x4 acc = rp[0];
#pragma unroll
            for (int i = 1; i < 16; ++i) {
                const f32x4 v = rp[i];
                acc.x = fmaxf(acc.x, v.x);
                acc.y = fmaxf(acc.y, v.y);
                acc.z = fmaxf(acc.z, v.z);
                acc.w = fmaxf(acc.w, v.w);
            }
            const float gmax = fmaxf(fmaxf(acc.x, acc.y), fmaxf(acc.z, acc.w));

            // local lowest idx matching gmax (descending -> lowest r wins)
            int bl = 0x7fffffff;
#pragma unroll
            for (int r = 15; r >= 0; --r) {
                bl = (mind[r] == gmax) ? (r * 64 + l) : bl;
            }
            unsigned long long mball = __ballot(bl != 0x7fffffff);
            int best = 0x7fffffff;
            while (mball) {                      // wave-uniform; expected 1 iter
                const int ln = (int)__ffsll(mball) - 1;
                const int cand = __builtin_amdgcn_readlane(bl, ln);
                best = cand < best ? cand : best;
                mball &= (mball - 1);
            }
            gi = best;
        }
        return;
    }

    // ---------------- weight prep: 32x32 tile transpose + split ----------------
    int tid = bid - BB;
    const float* src;
    unsigned short *dh, *dl;
    int N, Kp, koff, kt, nt;
    if (tid < 32) {
        src = W1b; dh = W1bt_h; dl = W1bt_l; N = 256; Kp = KP1; koff = 0;
        kt = tid >> 3; nt = tid & 7;
    } else if (tid < 160) {
        tid -= 32;
        src = W2a; dh = W2at_h; dl = W2at_l; N = 512; Kp = KP2; koff = 256;
        kt = tid >> 4; nt = tid & 15;
    } else {
        tid -= 160;
        src = W2b; dh = W2bt_h; dl = W2bt_l; N = 384; Kp = KP3; koff = 0;
        kt = tid / 12; nt = tid % 12;
    }
    const int k0 = kt * 32, n0 = nt * 32;
    const int tx = threadIdx.x & 31, ty = threadIdx.x >> 5;
#pragma unroll
    for (int i = 0; i < 4; ++i) {
        const int kl = ty + i * 8;
        tile[kl][tx] = src[(size_t)(k0 + kl + koff) * N + n0 + tx];
    }
    __syncthreads();
#pragma unroll
    for (int i = 0; i < 4; ++i) {
        const int nl = ty + i * 8;
        const float x = tile[tx][nl];
        const unsigned short hi = f2bf(x);
        const unsigned short lo = f2bf(x - bf2f(hi));
        const size_t o = (size_t)(n0 + nl) * Kp + k0 + tx;
        dh[o] = hi;
        dl[o] = lo;
    }
}

// ---------------------------------------------------------------------------
// kNN: wave-per-seed, shfl butterfly argmin (verified rounds 3-4).
// ---------------------------------------------------------------------------
__global__ __launch_bounds__(512) void knn_kernel(
    const float* __restrict__ pos,
    const float* __restrict__ seed_pos,
    int* __restrict__ nbr)
{
    __shared__ float sx_[NN], sy_[NN], sz_[NN];
    const int blk = blockIdx.x;            // 0..127
    const int b   = blk >> 4;
    const int t   = threadIdx.x;
    const int w   = t >> 6;
    const int l   = t & 63;
    const float* p = pos + (size_t)b * NN * 3;

    for (int i = t; i < NN; i += 512) {
        sx_[i] = p[i * 3 + 0];
        sy_[i] = p[i * 3 + 1];
        sz_[i] = p[i * 3 + 2];
    }
    __syncthreads();

    const int gsid = b * SS + (blk & 15) * 8 + w;
    const float cx = seed_pos[gsid * 3 + 0];
    const float cy = seed_pos[gsid * 3 + 1];
    const float cz = seed_pos[gsid * 3 + 2];

    float d[16];
#pragma unroll
    for (int r = 0; r < 16; ++r) {
        const int i = r * 64 + l;
        const float dx = __fsub_rn(sx_[i], cx);
        const float dy = __fsub_rn(sy_[i], cy);
        const float dz = __fsub_rn(sz_[i], cz);
        d[r] = __fadd_rn(__fadd_rn(__fmul_rn(dx, dx), __fmul_rn(dy, dy)),
                         __fmul_rn(dz, dz));
    }

    for (int it = 0; it < KK; ++it) {
        float best = INFINITY;
        int bi = NN;
#pragma unroll
        for (int r = 0; r < 16; ++r) {
            if (d[r] < best) { best = d[r]; bi = r * 64 + l; }
        }
#pragma unroll
        for (int off = 1; off < 64; off <<= 1) {
            const float ov = __shfl_xor(best, off);
            const int   oi = __shfl_xor(bi, off);
            if (ov < best || (ov == best && oi < bi)) { best = ov; bi = oi; }
        }
        const int wr = bi >> 6, wl = bi & 63;
#pragma unroll
        for (int r = 0; r < 16; ++r) {
            if (r == wr && l == wl) d[r] = INFINITY;
        }
        if (l == 0) nbr[(size_t)gsid * KK + it] = bi;
    }
}

// ---------------------------------------------------------------------------
// PointConv, M=64 (2 seeds per block), 8 waves (512 threads) — verified R4.
// ---------------------------------------------------------------------------
__global__ __launch_bounds__(512, 2) void conv_kernel(
    const float* __restrict__ pos,
    const float* __restrict__ seed_pos,
    const int* __restrict__ nbr,
    const float* __restrict__ W1a, const float* __restrict__ b1a,
    const float* __restrict__ b1b,
    const float* __restrict__ W2a, const float* __restrict__ b2a,
    const float* __restrict__ b2b,
    const unsigned short* __restrict__ W1bt_h, const unsigned short* __restrict__ W1bt_l,
    const unsigned short* __restrict__ W2at_h, const unsigned short* __restrict__ W2at_l,
    const unsigned short* __restrict__ W2bt_h, const unsigned short* __restrict__ W2bt_l,
    float* __restrict__ out)
{
    __shared__ __align__(16) unsigned char smem[105216];
    unsigned char* sH1h = smem;
    unsigned char* sH1l = smem + 16384;
    unsigned char* sA2h = smem + 32768;
    unsigned char* sA2l = smem + 65536;
    unsigned char* sA3h = smem;
    unsigned char* sA3l = smem + 32768;
    float* s_g    = (float*)(smem + 98304);    // [2][256]
    float* s_base = (float*)(smem + 100352);   // [2][512]
    float* s_rel  = (float*)(smem + 104448);   // [64][3]

    const int blk = blockIdx.x;                // seeds blk*2, blk*2+1
    const int t   = threadIdx.x;
    const int w   = t >> 6;
    const int l   = t & 63;
    const int lg  = l >> 4;
    const int l15 = l & 15;

    // ---- stage 0: gather rel for 64 rows (2 seeds x 32 neighbors) ----
    if (t < 64) {
        const int sl   = t >> 5;
        const int gsid = blk * 2 + sl;
        const int b    = gsid >> 7;
        const int pi   = nbr[(size_t)gsid * KK + (t & 31)];
        const float* pp = pos + ((size_t)b * NN + pi) * 3;
        s_rel[t * 3 + 0] = pp[0] - seed_pos[gsid * 3 + 0];
        s_rel[t * 3 + 1] = pp[1] - seed_pos[gsid * 3 + 1];
        s_rel[t * 3 + 2] = pp[2] - seed_pos[gsid * 3 + 2];
    }
    __syncthreads();

    // ---- stage 1: h1[64][128] = relu(rel@W1a + b1a) -> H1 hi/lo swizzled ----
    {
        const int j  = t & 127;
        const int rg = t >> 7;
        const float w0 = W1a[j], w1 = W1a[128 + j], w2 = W1a[256 + j], bb = b1a[j];
#pragma unroll
        for (int rr = 0; rr < 16; ++rr) {
            const int row = rg * 16 + rr;
            float v = fmaf(s_rel[row * 3 + 2], w2,
                      fmaf(s_rel[row * 3 + 1], w1,
                      fmaf(s_rel[row * 3 + 0], w0, bb)));
            v = fmaxf(v, 0.0f);
            const unsigned short hi = f2bf(v);
            const unsigned short lo = f2bf(v - bf2f(hi));
            const int byte = (j * 2) ^ ((row & 7) << 4);
            *(unsigned short*)(sH1h + row * 256 + byte) = hi;
            *(unsigned short*)(sH1l + row * 256 + byte) = lo;
        }
    }
    __syncthreads();

    // ---- GEMM1: f = h1 @ W1b (M=64,N=256,K=128) ----
    {
        f32x4 C1[4][2];
#pragma unroll
        for (int m = 0; m < 4; ++m)
#pragma unroll
            for (int i = 0; i < 2; ++i) C1[m][i] = (f32x4){0.f, 0.f, 0.f, 0.f};
#pragma unroll
        for (int ks = 0; ks < 4; ++ks) {
            s16x8 ah[4], al[4], bh[2], bl[2];
#pragma unroll
            for (int m = 0; m < 4; ++m) {
                const int row = m * 16 + l15;
                const int byte = (lg * 16 + ks * 64) ^ ((row & 7) << 4);
                ah[m] = *(const s16x8*)(sH1h + row * 256 + byte);
                al[m] = *(const s16x8*)(sH1l + row * 256 + byte);
            }
#pragma unroll
            for (int i = 0; i < 2; ++i) {
                const int ncol = w * 32 + i * 16 + l15;
                const size_t off = (size_t)ncol * KP1 + lg * 8 + ks * 32;
                bh[i] = *(const s16x8*)(W1bt_h + off);
                bl[i] = *(const s16x8*)(W1bt_l + off);
            }
#pragma unroll
            for (int i = 0; i < 2; ++i)
#pragma unroll
                for (int m = 0; m < 4; ++m) C1[m][i] = mfma16(ah[m], bh[i], C1[m][i]);
#pragma unroll
            for (int i = 0; i < 2; ++i)
#pragma unroll
                for (int m = 0; m < 4; ++m) C1[m][i] = mfma16(ah[m], bl[i], C1[m][i]);
#pragma unroll
            for (int i = 0; i < 2; ++i)
#pragma unroll
                for (int m = 0; m < 4; ++m) C1[m][i] = mfma16(al[m], bh[i], C1[m][i]);
        }
#pragma unroll
        for (int i = 0; i < 2; ++i) {
            const int col = w * 32 + i * 16 + l15;
            const float bias = b1b[col];
            float pm0 = -INFINITY, pm1 = -INFINITY;
#pragma unroll
            for (int m = 0; m < 4; ++m)
#pragma unroll
                for (int r = 0; r < 4; ++r) {
                    const float v = C1[m][i][r] + bias;
                    if (m < 2) pm0 = fmaxf(pm0, v); else pm1 = fmaxf(pm1, v);
                    const int row = m * 16 + lg * 4 + r;
                    const unsigned short hi = f2bf(v);
                    const unsigned short lo = f2bf(v - bf2f(hi));
                    const int byte = (col * 2) ^ ((row & 7) << 4);
                    *(unsigned short*)(sA2h + row * 512 + byte) = hi;
                    *(unsigned short*)(sA2l + row * 512 + byte) = lo;
                }
            pm0 = fmaxf(pm0, __shfl_xor(pm0, 16));
            pm0 = fmaxf(pm0, __shfl_xor(pm0, 32));
            pm1 = fmaxf(pm1, __shfl_xor(pm1, 16));
            pm1 = fmaxf(pm1, __shfl_xor(pm1, 32));
            if (lg == 0) { s_g[col] = pm0; s_g[256 + col] = pm1; }
        }
    }
    __syncthreads();

    // ---- base[seed][c] = b2a[c] + g_seed @ W2a[0:256] ----
    {
        const int c = t;
        float a0 = b2a[c], a1 = b2a[c];
#pragma unroll 4
        for (int jj = 0; jj < 256; ++jj) {
            const float w_ = W2a[(size_t)jj * 512 + c];
            a0 = fmaf(s_g[jj],       w_, a0);
            a1 = fmaf(s_g[256 + jj], w_, a1);
        }
        s_base[c] = a0;
        s_base[512 + c] = a1;
    }
    __syncthreads();

    // ---- GEMM2: C2 = f @ W2a[256:] (M=64,N=512,K=256) ----
    f32x4 C2[4][4];
#pragma unroll
    for (int m = 0; m < 4; ++m)
#pragma unroll
        for (int n = 0; n < 4; ++n) C2[m][n] = (f32x4){0.f, 0.f, 0.f, 0.f};
#pragma unroll 2
    for (int ks = 0; ks < 8; ++ks) {
        s16x8 ah[4], al[4];
#pragma unroll
        for (int m = 0; m < 4; ++m) {
            const int row = m * 16 + l15;
            const int byte = (lg * 16 + ks * 64) ^ ((row & 7) << 4);
            ah[m] = *(const s16x8*)(sA2h + row * 512 + byte);
            al[m] = *(const s16x8*)(sA2l + row * 512 + byte);
        }
#pragma unroll
        for (int n = 0; n < 4; ++n) {
            const int ncol = n * 128 + w * 16 + l15;
            const size_t off = (size_t)ncol * KP2 + lg * 8 + ks * 32;
            const s16x8 bh = *(const s16x8*)(W2at_h + off);
            const s16x8 bl = *(const s16x8*)(W2at_l + off);
#pragma unroll
            for (int m = 0; m < 4; ++m) C2[m][n] = mfma16(ah[m], bh, C2[m][n]);
#pragma unroll
            for (int m = 0; m < 4; ++m) C2[m][n] = mfma16(ah[m], bl, C2[m][n]);
#pragma unroll
            for (int m = 0; m < 4; ++m) C2[m][n] = mfma16(al[m], bh, C2[m][n]);
        }
    }
    __syncthreads();

    // ---- GEMM3: e = h2 @ W2b, K-split through one 64KB staging buffer ----
    f32x4 C3[4][3];
#pragma unroll
    for (int m = 0; m < 4; ++m)
#pragma unroll
        for (int n = 0; n < 3; ++n) C3[m][n] = (f32x4){0.f, 0.f, 0.f, 0.f};

#pragma unroll
    for (int h = 0; h < 2; ++h) {
#pragma unroll
        for (int q = 0; q < 2; ++q) {
            const int n = 2 * h + q;
            const int col  = n * 128 + w * 16 + l15;
            const int colL = q * 128 + w * 16 + l15;
            const float bs0 = s_base[col];
            const float bs1 = s_base[512 + col];
#pragma unroll
            for (int m = 0; m < 4; ++m)
#pragma unroll
                for (int r = 0; r < 4; ++r) {
                    const float v = fmaxf(C2[m][n][r] + (m < 2 ? bs0 : bs1), 0.0f);
                    const int row = m * 16 + lg * 4 + r;
                    const unsigned short hi = f2bf(v);
                    const unsigned short lo = f2bf(v - bf2f(hi));
                    const int byte = (colL * 2) ^ ((row & 7) << 4);
                    *(unsigned short*)(sA3h + row * 512 + byte) = hi;
                    *(unsigned short*)(sA3l + row * 512 + byte) = lo;
                }
        }
        __syncthreads();

        const int koff = h * 256;
#pragma unroll 2
        for (int ks = 0; ks < 8; ++ks) {
            s16x8 ah[4], al[4];
#pragma unroll
            for (int m = 0; m < 4; ++m) {
                const int row = m * 16 + l15;
                const int byte = (lg * 16 + ks * 64) ^ ((row & 7) << 4);
                ah[m] = *(const s16x8*)(sA3h + row * 512 + byte);
                al[m] = *(const s16x8*)(sA3l + row * 512 + byte);
            }
#pragma unroll
            for (int n = 0; n < 3; ++n) {
                const int ncol = w * 48 + n * 16 + l15;
                const size_t off = (size_t)ncol * KP3 + koff + lg * 8 + ks * 32;
                const s16x8 bh = *(const s16x8*)(W2bt_h + off);
                const s16x8 bl = *(const s16x8*)(W2bt_l + off);
#pragma unroll
                for (int m = 0; m < 4; ++m) C3[m][n] = mfma16(ah[m], bh, C3[m][n]);
#pragma unroll
                for (int m = 0; m < 4; ++m) C3[m][n] = mfma16(ah[m], bl, C3[m][n]);
#pragma unroll
                for (int m = 0; m < 4; ++m) C3[m][n] = mfma16(al[m], bh, C3[m][n]);
            }
        }
        if (h == 0) __syncthreads();
    }

    // ---- epilogue: out[seed] = colmax(e_seed) + b2b ----
#pragma unroll
    for (int n = 0; n < 3; ++n) {
        const int col = w * 48 + n * 16 + l15;
        float pm0 = -INFINITY, pm1 = -INFINITY;
#pragma unroll
        for (int m = 0; m < 4; ++m)
#pragma unroll
            for (int r = 0; r < 4; ++r) {
                if (m < 2) pm0 = fmaxf(pm0, C3[m][n][r]);
                else       pm1 = fmaxf(pm1, C3[m][n][r]);
            }
        pm0 = fmaxf(pm0, __shfl_xor(pm0, 16));
        pm0 = fmaxf(pm0, __shfl_xor(pm0, 32));
        pm1 = fmaxf(pm1, __shfl_xor(pm1, 16));
        pm1 = fmaxf(pm1, __shfl_xor(pm1, 32));
        if (lg == 0) {
            out[(size_t)(blk * 2 + 0) * EMB + col] = pm0 + b2b[col];
            out[(size_t)(blk * 2 + 1) * EMB + col] = pm1 + b2b[col];
        }
    }
}

// ---------------------------------------------------------------------------
extern "C" void kernel_launch(void* const* d_in, const int* in_sizes, int n_in,
                              void* d_out, int out_size, void* d_ws, size_t ws_size,
                              hipStream_t stream)
{
    const float* pos = (const float*)d_in[0];
    const float* W1a = (const float*)d_in[2];
    const float* b1a = (const float*)d_in[3];
    const float* W1b = (const float*)d_in[4];
    const float* b1b = (const float*)d_in[5];
    const float* W2a = (const float*)d_in[6];
    const float* b2a = (const float*)d_in[7];
    const float* W2b = (const float*)d_in[8];
    const float* b2b = (const float*)d_in[9];
    float* out = (float*)d_out;

    unsigned char* ws = (unsigned char*)d_ws;
    float* seed_pos = (float*)(ws + 0);                         // 12 KB
    int*   nbr      = (int*)(ws + 16384);                       // 128 KB
    unsigned short* W1bt_h = (unsigned short*)(ws + 147456);    // [256][136]
    unsigned short* W1bt_l = (unsigned short*)(ws + 217088);
    unsigned short* W2at_h = (unsigned short*)(ws + 286720);    // [512][264]
    unsigned short* W2at_l = (unsigned short*)(ws + 557056);
    unsigned short* W2bt_h = (unsigned short*)(ws + 827392);    // [384][520]
    unsigned short* W2bt_l = (unsigned short*)(ws + 1226752);

    pre_kernel<<<BB + 352, 256, 0, stream>>>(pos, seed_pos, W1b, W2a, W2b,
                                             W1bt_h, W1bt_l, W2at_h, W2at_l,
                                             W2bt_h, W2bt_l);
    knn_kernel<<<BB * SS / 8, 512, 0, stream>>>(pos, seed_pos, nbr);
    conv_kernel<<<BB * SS / 2, 512, 0, stream>>>(pos, seed_pos, nbr,
                                                 W1a, b1a, b1b, W2a, b2a, b2b,
                                                 W1bt_h, W1bt_l, W2at_h, W2at_l,
                                                 W2bt_h, W2bt_l, out);
}